// Round 3
// baseline (448.256 us; speedup 1.0000x reference)
//
#include <hip/hip_runtime.h>
#include <hip/hip_bf16.h>
#include <stdint.h>

#define N 4096

typedef __attribute__((ext_vector_type(4))) float f32x4;
typedef __attribute__((ext_vector_type(8))) short s16x8;   // 8 bf16 lanes (4 VGPRs)

__device__ inline unsigned short f2bf(float f) {
    unsigned int u = __float_as_uint(f);
    u += 0x7fffu + ((u >> 16) & 1u);        // RNE
    return (unsigned short)(u >> 16);
}
__device__ inline float bf2f(unsigned short h) {
    return __uint_as_float(((unsigned int)h) << 16);
}

// ---------------- k0a: T = w3@w2 [64][256] per graph, b_eff = w3@(w2@b1+b2)+b3 ----------------
__global__ void k0a(const float* __restrict__ w2a, const float* __restrict__ w3a,
                    const float* __restrict__ b1a, const float* __restrict__ b2a, const float* __restrict__ b3a,
                    const float* __restrict__ w2b, const float* __restrict__ w3b,
                    const float* __restrict__ b1b, const float* __restrict__ b2b, const float* __restrict__ b3b,
                    float* __restrict__ T, float* __restrict__ beff) {
    const int g  = blockIdx.x >> 5;
    const int nb = blockIdx.x & 31;
    const float* w2 = g ? w2b : w2a;   // [128][256]
    const float* w3 = g ? w3b : w3a;   // [64][128]
    const int c  = threadIdx.x;
    const int n0 = nb * 2;
    float a0 = 0.f, a1 = 0.f;
#pragma unroll 4
    for (int r = 0; r < 128; ++r) {
        float w = w2[r * 256 + c];
        a0 += w3[n0 * 128 + r] * w;            // block-uniform -> s_load
        a1 += w3[n0 * 128 + 128 + r] * w;
    }
    float* Tg = T + g * 64 * 256;
    Tg[n0 * 256 + c]       = a0;
    Tg[(n0 + 1) * 256 + c] = a1;

    if (nb == 0) {                              // bias path (biases zero in setup; compute anyway)
        __shared__ float u[128];
        const float* b1 = g ? b1b : b1a;
        const float* b2 = g ? b2b : b2a;
        const float* b3 = g ? b3b : b3a;
        if (threadIdx.x < 128) {
            int r = threadIdx.x;
            float s = 0.f;
            for (int cc = 0; cc < 256; ++cc) s += w2[r * 256 + cc] * b1[cc];
            u[r] = s + b2[r];
        }
        __syncthreads();
        if (threadIdx.x < 64) {
            int n = threadIdx.x;
            float s = 0.f;
            for (int r = 0; r < 128; ++r) s += w3[n * 128 + r] * u[r];
            beff[g * 64 + n] = s + b3[n];
        }
    }
}

// ---------------- k0b: Weff = T@w1 -> split bf16 (hi + lo planes), n-major ----------------
__global__ void k0b(const float* __restrict__ w1a, const float* __restrict__ w1b,
                    const float* __restrict__ T,
                    unsigned short* __restrict__ Whi, unsigned short* __restrict__ Wlo) {
    const int b  = blockIdx.x;
    const int g  = b >> 7, n8 = (b >> 4) & 7, kc = b & 15;
    const float* w1 = g ? w1b : w1a;                  // [256][4096]
    const float* Tg = T + (g * 64 + n8 * 8) * 256;    // block-uniform rows -> s_load
    const int kx = kc * 256 + threadIdx.x;
    float acc[8] = {0, 0, 0, 0, 0, 0, 0, 0};
    for (int r = 0; r < 256; ++r) {
        float w = w1[r * N + kx];
#pragma unroll
        for (int j = 0; j < 8; ++j) acc[j] += Tg[j * 256 + r] * w;
    }
#pragma unroll
    for (int j = 0; j < 8; ++j) {
        size_t idx = (size_t)(g * 64 + n8 * 8 + j) * N + kx;
        unsigned short hi = f2bf(acc[j]);
        Whi[idx] = hi;
        Wlo[idx] = f2bf(acc[j] - bf2f(hi));
    }
}

// ---------------- k1: h = relu(x @ Weff.T + beff), split-bf16 (3 MFMA) for ~fp32 precision ----------------
__global__ __launch_bounds__(256) void k1(const float* __restrict__ x1, const float* __restrict__ x2,
                                          const unsigned short* __restrict__ Whi,
                                          const unsigned short* __restrict__ Wlo,
                                          const float* __restrict__ beff,
                                          float* __restrict__ hf, unsigned short* __restrict__ hT) {
    const int b  = blockIdx.x;
    const int g  = b & 1;
    const int i0 = (b >> 1) * 16;
    const float* x = g ? x2 : x1;
    const size_t goff = (size_t)g * 64 * N;

    __shared__ unsigned short Ah[16 * 72], Al[16 * 72];   // pad 64->72: 2-way banks (free)
    __shared__ unsigned short Bh[64 * 72], Bl[64 * 72];

    const int t = threadIdx.x;
    const int lane = t & 63, w = t >> 6;
    const int arow = t >> 4, ac4 = (t & 15) * 4;
    const int brow = (t * 16) >> 7, bkh = ((t * 16) & 127) >> 1;   // B: 128B rows, 2 issues (+32 rows)
    const int q = lane >> 4, l15 = lane & 15;

    f32x4 acc = {0.f, 0.f, 0.f, 0.f};

    for (int kk = 0; kk < 64; ++kk) {
        const int k0 = kk * 64;
        float4 av  = *(const float4*)&x[(size_t)(i0 + arow) * N + k0 + ac4];
        uint4  bh0 = *(const uint4*)&Whi[goff + (size_t)brow * N + k0 + bkh];
        uint4  bh1 = *(const uint4*)&Whi[goff + (size_t)(brow + 32) * N + k0 + bkh];
        uint4  bl0 = *(const uint4*)&Wlo[goff + (size_t)brow * N + k0 + bkh];
        uint4  bl1 = *(const uint4*)&Wlo[goff + (size_t)(brow + 32) * N + k0 + bkh];
        __syncthreads();   // prior compute done reading LDS
        unsigned short hx = f2bf(av.x), hy = f2bf(av.y), hz = f2bf(av.z), hw = f2bf(av.w);
        unsigned short lx = f2bf(av.x - bf2f(hx)), ly = f2bf(av.y - bf2f(hy));
        unsigned short lz = f2bf(av.z - bf2f(hz)), lw = f2bf(av.w - bf2f(hw));
        *(uint2*)&Ah[arow * 72 + ac4] = make_uint2((unsigned)hx | ((unsigned)hy << 16),
                                                   (unsigned)hz | ((unsigned)hw << 16));
        *(uint2*)&Al[arow * 72 + ac4] = make_uint2((unsigned)lx | ((unsigned)ly << 16),
                                                   (unsigned)lz | ((unsigned)lw << 16));
        *(uint4*)&Bh[brow * 72 + bkh] = bh0;
        *(uint4*)&Bh[(brow + 32) * 72 + bkh] = bh1;
        *(uint4*)&Bl[brow * 72 + bkh] = bl0;
        *(uint4*)&Bl[(brow + 32) * 72 + bkh] = bl1;
        __syncthreads();
#pragma unroll
        for (int c = 0; c < 2; ++c) {
            const int kf = c * 32 + q * 8;
            s16x8 ah = *(const s16x8*)&Ah[l15 * 72 + kf];
            s16x8 al = *(const s16x8*)&Al[l15 * 72 + kf];
            s16x8 bh = *(const s16x8*)&Bh[(w * 16 + l15) * 72 + kf];
            s16x8 bl = *(const s16x8*)&Bl[(w * 16 + l15) * 72 + kf];
            acc = __builtin_amdgcn_mfma_f32_16x16x32_bf16(al, bh, acc, 0, 0, 0);
            acc = __builtin_amdgcn_mfma_f32_16x16x32_bf16(ah, bl, acc, 0, 0, 0);
            acc = __builtin_amdgcn_mfma_f32_16x16x32_bf16(ah, bh, acc, 0, 0, 0);
        }
    }

    const int n = w * 16 + l15;
    const float be = beff[g * 64 + n];
    unsigned short pk[4];
#pragma unroll
    for (int r = 0; r < 4; ++r) {
        int i = i0 + q * 4 + r;
        float v = acc[r] + be;
        v = fmaxf(v, 0.f);
        hf[(size_t)(g * N + i) * 64 + n] = v;
        pk[r] = f2bf(v);
    }
    *(ushort4*)&hT[(size_t)(g * 64 + n) * N + i0 + q * 4] = make_ushort4(pk[0], pk[1], pk[2], pk[3]);
}

// ---------------- k2: both graphs; agg = (adj==1)*alpha @ h via MFMA; deg in-block; fused epilogue ----------------
__global__ __launch_bounds__(256) void k2(const int* __restrict__ adj1, const int* __restrict__ adj2,
                                          const float* __restrict__ alpha, const float* __restrict__ Wp,
                                          const unsigned short* __restrict__ hT, const float* __restrict__ hf,
                                          float* __restrict__ outv) {
    const int i0 = blockIdx.x * 16;
    __shared__ unsigned short A1s[16 * 72], A2s[16 * 72];
    __shared__ unsigned short B1s[64 * 72], B2s[64 * 72];
    __shared__ float degred[2 * 256];
    __shared__ float degs[2 * 16];

    const int t = threadIdx.x;
    const int lane = t & 63, w = t >> 6;
    const int arow = t >> 4, ac4 = (t & 15) * 4;
    const int brow = (t * 16) >> 7, bkh = ((t * 16) & 127) >> 1;
    const int q = lane >> 4, l15 = lane & 15;

    f32x4 acc1 = {0.f, 0.f, 0.f, 0.f}, acc2 = {0.f, 0.f, 0.f, 0.f};
    int deg1 = 0, deg2 = 0;

    for (int kk = 0; kk < 64; ++kk) {
        const int k0 = kk * 64;
        const size_t aidx = (size_t)(i0 + arow) * N + k0 + ac4;
        float4 al = *(const float4*)&alpha[aidx];
        int4 j1 = *(const int4*)&adj1[aidx];
        int4 j2 = *(const int4*)&adj2[aidx];
        uint4 b10 = *(const uint4*)&hT[(size_t)brow * N + k0 + bkh];
        uint4 b11 = *(const uint4*)&hT[(size_t)(brow + 32) * N + k0 + bkh];
        uint4 b20 = *(const uint4*)&hT[(size_t)(64 + brow) * N + k0 + bkh];
        uint4 b21 = *(const uint4*)&hT[(size_t)(64 + brow + 32) * N + k0 + bkh];
        unsigned short bx = f2bf(al.x), by = f2bf(al.y), bz = f2bf(al.z), bw = f2bf(al.w);
        __syncthreads();
        unsigned int lo1 = (j1.x == 1 ? (unsigned int)bx : 0u) | ((j1.y == 1 ? (unsigned int)by : 0u) << 16);
        unsigned int hi1 = (j1.z == 1 ? (unsigned int)bz : 0u) | ((j1.w == 1 ? (unsigned int)bw : 0u) << 16);
        unsigned int lo2 = (j2.x == 1 ? (unsigned int)bx : 0u) | ((j2.y == 1 ? (unsigned int)by : 0u) << 16);
        unsigned int hi2 = (j2.z == 1 ? (unsigned int)bz : 0u) | ((j2.w == 1 ? (unsigned int)bw : 0u) << 16);
        deg1 += (j1.x == 1) + (j1.y == 1) + (j1.z == 1) + (j1.w == 1);
        deg2 += (j2.x == 1) + (j2.y == 1) + (j2.z == 1) + (j2.w == 1);
        *(uint2*)&A1s[arow * 72 + ac4] = make_uint2(lo1, hi1);
        *(uint2*)&A2s[arow * 72 + ac4] = make_uint2(lo2, hi2);
        *(uint4*)&B1s[brow * 72 + bkh] = b10;
        *(uint4*)&B1s[(brow + 32) * 72 + bkh] = b11;
        *(uint4*)&B2s[brow * 72 + bkh] = b20;
        *(uint4*)&B2s[(brow + 32) * 72 + bkh] = b21;
        __syncthreads();
#pragma unroll
        for (int c = 0; c < 2; ++c) {
            const int kf = c * 32 + q * 8;
            s16x8 a1f = *(const s16x8*)&A1s[l15 * 72 + kf];
            s16x8 b1f = *(const s16x8*)&B1s[(w * 16 + l15) * 72 + kf];
            acc1 = __builtin_amdgcn_mfma_f32_16x16x32_bf16(a1f, b1f, acc1, 0, 0, 0);
            s16x8 a2f = *(const s16x8*)&A2s[l15 * 72 + kf];
            s16x8 b2f = *(const s16x8*)&B2s[(w * 16 + l15) * 72 + kf];
            acc2 = __builtin_amdgcn_mfma_f32_16x16x32_bf16(a2f, b2f, acc2, 0, 0, 0);
        }
    }

    degred[t]       = (float)deg1;   // [g][row][16 slices] == [g][t]
    degred[256 + t] = (float)deg2;
    __syncthreads();
    if (t < 32) {
        int g = t >> 4, r = t & 15;
        float s = 0.f;
        for (int j = 0; j < 16; ++j) s += degred[g * 256 + r * 16 + j];
        degs[g * 16 + r] = s;
    }
    __syncthreads();

    const float W00 = Wp[0];
    const int n = w * 16 + l15;
#pragma unroll
    for (int r = 0; r < 4; ++r) {
        int iloc = q * 4 + r;
        int i = i0 + iloc;
        float dg1 = degs[iloc];
        float hv1 = hf[(size_t)i * 64 + n];
        float v1 = (dg1 != 0.f) ? (acc1[r] * W00 / fmaxf(dg1, 1.f) + hv1) : 0.f;
        outv[(size_t)i * 64 + n] = v1;
        float dg2 = degs[16 + iloc];
        float hv2 = hf[(size_t)(N + i) * 64 + n];
        float v2 = (dg2 != 0.f) ? (acc2[r] * W00 / fmaxf(dg2, 1.f) + hv2) : 0.f;
        outv[(size_t)(N + i) * 64 + n] = v2;
    }
}

// ---------------- k3a/k3b: out = feat @ clf_w.T + clf_b (two-stage deterministic reduction) ----------------
__global__ __launch_bounds__(256) void k3a(const float* __restrict__ feat, const float* __restrict__ clfw,
                                           float* __restrict__ part) {
    const int t = threadIdx.x;
    const size_t idx = (size_t)blockIdx.x * 2048 + (size_t)t * 8;
    float4 a0 = *(const float4*)&feat[idx];
    float4 a1 = *(const float4*)&feat[idx + 4];
    float4 c0 = *(const float4*)&clfw[idx];
    float4 c1 = *(const float4*)&clfw[idx + 4];
    float4 d0 = *(const float4*)&clfw[524288 + idx];
    float4 d1 = *(const float4*)&clfw[524288 + idx + 4];
    float s0 = a0.x * c0.x + a0.y * c0.y + a0.z * c0.z + a0.w * c0.w
             + a1.x * c1.x + a1.y * c1.y + a1.z * c1.z + a1.w * c1.w;
    float s1 = a0.x * d0.x + a0.y * d0.y + a0.z * d0.z + a0.w * d0.w
             + a1.x * d1.x + a1.y * d1.y + a1.z * d1.z + a1.w * d1.w;
    __shared__ float r0[256], r1[256];
    r0[t] = s0; r1[t] = s1;
    __syncthreads();
    for (int s = 128; s > 0; s >>= 1) {
        if (t < s) { r0[t] += r0[t + s]; r1[t] += r1[t + s]; }
        __syncthreads();
    }
    if (t == 0) { part[blockIdx.x * 2] = r0[0]; part[blockIdx.x * 2 + 1] = r1[0]; }
}

__global__ void k3b(const float* __restrict__ part, const float* __restrict__ clfb,
                    float* __restrict__ outp) {
    const int t = threadIdx.x;
    __shared__ float r0[256], r1[256];
    r0[t] = part[t * 2]; r1[t] = part[t * 2 + 1];
    __syncthreads();
    for (int s = 128; s > 0; s >>= 1) {
        if (t < s) { r0[t] += r0[t + s]; r1[t] += r1[t + s]; }
        __syncthreads();
    }
    if (t == 0) { outp[0] = r0[0] + clfb[0]; outp[1] = r1[0] + clfb[1]; }
}

extern "C" void kernel_launch(void* const* d_in, const int* in_sizes, int n_in,
                              void* d_out, int out_size, void* d_ws, size_t ws_size,
                              hipStream_t stream) {
    const float* x1   = (const float*)d_in[0];
    const float* x2   = (const float*)d_in[1];
    const int*   adj1 = (const int*)d_in[2];
    const int*   adj2 = (const int*)d_in[3];
    const float* e1w1 = (const float*)d_in[4];
    const float* e1b1 = (const float*)d_in[5];
    const float* e1w2 = (const float*)d_in[6];
    const float* e1b2 = (const float*)d_in[7];
    const float* e1w3 = (const float*)d_in[8];
    const float* e1b3 = (const float*)d_in[9];
    const float* e2w1 = (const float*)d_in[10];
    const float* e2b1 = (const float*)d_in[11];
    const float* e2w2 = (const float*)d_in[12];
    const float* e2b2 = (const float*)d_in[13];
    const float* e2w3 = (const float*)d_in[14];
    const float* e2b3 = (const float*)d_in[15];
    const float* Wp   = (const float*)d_in[16];
    const float* alph = (const float*)d_in[17];
    const float* clfw = (const float*)d_in[18];
    const float* clfb = (const float*)d_in[19];

    char* wsb = (char*)d_ws;
    // Weff hi/lo (2 MB) live through k1; newv (2 MB) aliases them from k2 on.
    unsigned short* Whi = (unsigned short*)(wsb);                        // 1 MB
    unsigned short* Wlo = (unsigned short*)(wsb + (1u << 20));           // 1 MB
    float* newv = (float*)(wsb);                                         // 2 MB (aliases Whi/Wlo)
    unsigned short* hT  = (unsigned short*)(wsb + (2u << 20));           // 1 MB
    float* hf   = (float*)(wsb + (3u << 20));                            // 2 MB
    float* T    = (float*)(wsb + (5u << 20));                            // 128 KB
    float* beff = (float*)(wsb + (5u << 20) + (1u << 17));               // 512 B
    float* part = (float*)(wsb + (5u << 20) + (1u << 17) + 4096);        // 2 KB

    hipLaunchKernelGGL(k0a, dim3(64), dim3(256), 0, stream,
                       e1w2, e1w3, e1b1, e1b2, e1b3, e2w2, e2w3, e2b1, e2b2, e2b3, T, beff);
    hipLaunchKernelGGL(k0b, dim3(256), dim3(256), 0, stream, e1w1, e2w1, T, Whi, Wlo);
    hipLaunchKernelGGL(k1, dim3(512), dim3(256), 0, stream, x1, x2, Whi, Wlo, beff, hf, hT);
    hipLaunchKernelGGL(k2, dim3(256), dim3(256), 0, stream, adj1, adj2, alph, Wp, hT, hf, newv);
    hipLaunchKernelGGL(k3a, dim3(256), dim3(256), 0, stream, newv, clfw, part);
    hipLaunchKernelGGL(k3b, dim3(1), dim3(256), 0, stream, part, clfb, (float*)d_out);
}